// Round 1
// baseline (3975.822 us; speedup 1.0000x reference)
//
#include <hip/hip_runtime.h>

#define D 64

// SpMM scatter: one 64-lane wave per edge, lane d handles dimension d.
// x_dst[row[e]][d] += vals[e] * x_src[col[e]][d]
__global__ void spmm_scatter_kernel(const float* __restrict__ x_src,
                                    const int* __restrict__ row,
                                    const int* __restrict__ col,
                                    const float* __restrict__ vals,
                                    float* __restrict__ x_dst,
                                    int E) {
    int gid = blockIdx.x * blockDim.x + threadIdx.x;
    int e = gid >> 6;            // wave index = edge index
    int lane = threadIdx.x & 63; // dimension
    if (e >= E) return;
    int r = row[e];
    int c = col[e];
    float v = vals[e];
    float xv = x_src[(size_t)c * D + lane];
    atomicAdd(&x_dst[(size_t)r * D + lane], v * xv);
}

// Row L2-normalize x in place (next layer's input) and accumulate out += coef * x_norm.
// One 64-lane wave per row (D == wave size == 64).
__global__ void norm_accum_kernel(float* __restrict__ x,
                                  float* __restrict__ out,
                                  float coef,
                                  int N) {
    int gid = blockIdx.x * blockDim.x + threadIdx.x;
    int rowi = gid >> 6;
    int lane = threadIdx.x & 63;
    if (rowi >= N) return;
    size_t idx = (size_t)rowi * D + lane;
    float v = x[idx];
    float s = v * v;
    // full 64-lane butterfly reduction
    #pragma unroll
    for (int off = 32; off >= 1; off >>= 1) {
        s += __shfl_xor(s, off);
    }
    float norm = sqrtf(s);
    float inv = 1.0f / fmaxf(norm, 1e-12f);
    float nv = v * inv;
    x[idx] = nv;
    out[idx] += coef * nv;
}

extern "C" void kernel_launch(void* const* d_in, const int* in_sizes, int n_in,
                              void* d_out, int out_size, void* d_ws, size_t ws_size,
                              hipStream_t stream) {
    const float* in_embs = (const float*)d_in[0];
    const int*   row     = (const int*)d_in[1];
    const int*   col     = (const int*)d_in[2];
    const float* vals    = (const float*)d_in[3];
    // d_in[4] = n_layers (on device); reference constant N_LAYERS=3, hardcoded.

    const int N = in_sizes[0] / D;   // 150000
    const int E = in_sizes[1];       // 6000000

    float* out  = (float*)d_out;
    float* bufA = (float*)d_ws;
    float* bufB = bufA + (size_t)N * D;

    const size_t embBytes = (size_t)N * D * sizeof(float);

    // out = in_embs
    hipMemcpyAsync(out, in_embs, embBytes, hipMemcpyDeviceToDevice, stream);

    const float coefs[3] = {2.0f, 1.5f, 4.0f / 3.0f};

    dim3 block(256);                        // 4 waves per block
    dim3 sgrid((unsigned)((E + 3) / 4));    // one wave per edge
    dim3 ngrid((unsigned)((N + 3) / 4));    // one wave per row

    const float* src = in_embs;
    float* dst   = bufA;
    float* other = bufB;

    for (int i = 0; i < 3; ++i) {
        hipMemsetAsync(dst, 0, embBytes, stream);
        spmm_scatter_kernel<<<sgrid, block, 0, stream>>>(src, row, col, vals, dst, E);
        norm_accum_kernel<<<ngrid, block, 0, stream>>>(dst, out, coefs[i], N);
        src = dst;
        float* t = dst;
        dst = other;
        other = t;
    }
}

// Round 2
// 1505.717 us; speedup vs baseline: 2.6405x; 2.6405x over previous
//
#include <hip/hip_runtime.h>

#define D 64

// ---------------- CSR build ----------------

__global__ void count_deg_kernel(const int* __restrict__ row,
                                 int* __restrict__ deg, int E) {
    int e = blockIdx.x * blockDim.x + threadIdx.x;
    if (e < E) atomicAdd(&deg[row[e]], 1);
}

// Single-workgroup exclusive scan over N row degrees -> ptr[0..N]
__global__ __launch_bounds__(1024) void scan_kernel(const int* __restrict__ deg,
                                                    int* __restrict__ ptr, int N) {
    __shared__ int tmp[1024];
    int tid = threadIdx.x;
    int chunk = (N + 1023) >> 10;
    int beg = tid * chunk;
    int en = min(beg + chunk, N);
    int s = 0;
    for (int i = beg; i < en; ++i) s += deg[i];
    tmp[tid] = s;
    __syncthreads();
    // Hillis-Steele inclusive scan across 1024 partials
    for (int d = 1; d < 1024; d <<= 1) {
        int t = (tid >= d) ? tmp[tid - d] : 0;
        __syncthreads();
        tmp[tid] += t;
        __syncthreads();
    }
    int offset = tmp[tid] - s;  // exclusive prefix for this chunk
    for (int i = beg; i < en; ++i) { ptr[i] = offset; offset += deg[i]; }
    if (tid == 1023) ptr[N] = tmp[1023];
}

__global__ void scatter_edges_kernel(const int* __restrict__ row,
                                     const int* __restrict__ col,
                                     const float* __restrict__ vals,
                                     int* __restrict__ fill,
                                     int* __restrict__ ccol,
                                     float* __restrict__ cval, int E) {
    int e = blockIdx.x * blockDim.x + threadIdx.x;
    if (e < E) {
        int r = row[e];
        int pos = atomicAdd(&fill[r], 1);
        ccol[pos] = col[e];
        cval[pos] = vals[e];
    }
}

// ---------------- fused SpMM + L2-normalize (+ final combine) ----------------
// One 64-lane wave per row; lane = embedding dim.
template <bool FINAL>
__global__ void spmm_norm_kernel(const float* __restrict__ x_src,
                                 const int* __restrict__ ptr,
                                 const int* __restrict__ ccol,
                                 const float* __restrict__ cval,
                                 float* __restrict__ x_dst,         // !FINAL
                                 const float* __restrict__ in_embs, // FINAL
                                 const float* __restrict__ x1,      // FINAL
                                 float* __restrict__ out,           // FINAL
                                 int N) {
    int gid = blockIdx.x * blockDim.x + threadIdx.x;
    int r = gid >> 6;
    int lane = threadIdx.x & 63;
    if (r >= N) return;
    int s = ptr[r], e = ptr[r + 1];
    float acc = 0.f;
    int j = s;
    for (; j + 3 < e; j += 4) {
        int c0 = ccol[j], c1 = ccol[j + 1], c2 = ccol[j + 2], c3 = ccol[j + 3];
        float v0 = cval[j], v1 = cval[j + 1], v2 = cval[j + 2], v3 = cval[j + 3];
        acc += v0 * x_src[(size_t)c0 * D + lane];
        acc += v1 * x_src[(size_t)c1 * D + lane];
        acc += v2 * x_src[(size_t)c2 * D + lane];
        acc += v3 * x_src[(size_t)c3 * D + lane];
    }
    for (; j < e; ++j)
        acc += cval[j] * x_src[(size_t)ccol[j] * D + lane];

    float ss = acc * acc;
    #pragma unroll
    for (int off = 32; off >= 1; off >>= 1) ss += __shfl_xor(ss, off);
    float nv = acc / fmaxf(sqrtf(ss), 1e-12f);

    size_t idx = (size_t)r * D + lane;
    if (FINAL) {
        // out = in + 2*x1 + 1.5*x2 + (4/3)*x3 ; here x_src == x2, nv == x3
        out[idx] = in_embs[idx] + 2.0f * x1[idx] + 1.5f * x_src[idx]
                 + (4.0f / 3.0f) * nv;
    } else {
        x_dst[idx] = nv;
    }
}

// ---------------- fallback (round-0 atomic scatter path) ----------------

__global__ void spmm_scatter_kernel(const float* __restrict__ x_src,
                                    const int* __restrict__ row,
                                    const int* __restrict__ col,
                                    const float* __restrict__ vals,
                                    float* __restrict__ x_dst, int E) {
    int gid = blockIdx.x * blockDim.x + threadIdx.x;
    int e = gid >> 6;
    int lane = threadIdx.x & 63;
    if (e >= E) return;
    float xv = x_src[(size_t)col[e] * D + lane];
    atomicAdd(&x_dst[(size_t)row[e] * D + lane], vals[e] * xv);
}

__global__ void norm_accum_kernel(float* __restrict__ x, float* __restrict__ out,
                                  float coef, int N) {
    int gid = blockIdx.x * blockDim.x + threadIdx.x;
    int rowi = gid >> 6;
    int lane = threadIdx.x & 63;
    if (rowi >= N) return;
    size_t idx = (size_t)rowi * D + lane;
    float v = x[idx];
    float s = v * v;
    #pragma unroll
    for (int off = 32; off >= 1; off >>= 1) s += __shfl_xor(s, off);
    float nv = v / fmaxf(sqrtf(s), 1e-12f);
    x[idx] = nv;
    out[idx] += coef * nv;
}

extern "C" void kernel_launch(void* const* d_in, const int* in_sizes, int n_in,
                              void* d_out, int out_size, void* d_ws, size_t ws_size,
                              hipStream_t stream) {
    const float* in_embs = (const float*)d_in[0];
    const int*   row     = (const int*)d_in[1];
    const int*   col     = (const int*)d_in[2];
    const float* vals    = (const float*)d_in[3];
    // d_in[4] = n_layers (device scalar); reference constant N_LAYERS=3.

    const int N = in_sizes[0] / D;  // 150000
    const int E = in_sizes[1];      // 6000000

    float* out = (float*)d_out;

    const size_t embElems = (size_t)N * D;
    const size_t embBytes = embElems * sizeof(float);
    const size_t needed = 2 * embBytes + (size_t)E * 8 + ((size_t)N + 1) * 4 + (size_t)N * 4;

    dim3 block(256);
    dim3 egrid((unsigned)((E + 255) / 256));
    dim3 ngrid((unsigned)((N + 3) / 4));  // one wave per row, 4 waves/block

    if (ws_size >= needed) {
        char* wsb = (char*)d_ws;
        float* bufA   = (float*)wsb;                       wsb += embBytes;
        float* bufB   = (float*)wsb;                       wsb += embBytes;
        int*   ccol   = (int*)wsb;                         wsb += (size_t)E * 4;
        float* cval   = (float*)wsb;                       wsb += (size_t)E * 4;
        int*   ptr    = (int*)wsb;                         wsb += ((size_t)N + 1) * 4;
        int*   fill   = (int*)wsb;

        // CSR build
        hipMemsetAsync(fill, 0, (size_t)N * 4, stream);
        count_deg_kernel<<<egrid, block, 0, stream>>>(row, fill, E);
        scan_kernel<<<1, 1024, 0, stream>>>(fill, ptr, N);
        hipMemcpyAsync(fill, ptr, (size_t)N * 4, hipMemcpyDeviceToDevice, stream);
        scatter_edges_kernel<<<egrid, block, 0, stream>>>(row, col, vals, fill, ccol, cval, E);

        // layer 1: in_embs -> bufA (x1)
        spmm_norm_kernel<false><<<ngrid, block, 0, stream>>>(
            in_embs, ptr, ccol, cval, bufA, nullptr, nullptr, nullptr, N);
        // layer 2: bufA -> bufB (x2)
        spmm_norm_kernel<false><<<ngrid, block, 0, stream>>>(
            bufA, ptr, ccol, cval, bufB, nullptr, nullptr, nullptr, N);
        // layer 3: bufB -> out (fused final combine)
        spmm_norm_kernel<true><<<ngrid, block, 0, stream>>>(
            bufB, ptr, ccol, cval, nullptr, in_embs, bufA, out, N);
    } else {
        // fallback: round-0 path (needs 2 emb buffers)
        float* bufA = (float*)d_ws;
        float* bufB = bufA + embElems;
        hipMemcpyAsync(out, in_embs, embBytes, hipMemcpyDeviceToDevice, stream);
        const float coefs[3] = {2.0f, 1.5f, 4.0f / 3.0f};
        dim3 sgrid((unsigned)((E + 3) / 4));
        const float* src = in_embs;
        float* dst = bufA;
        float* other = bufB;
        for (int i = 0; i < 3; ++i) {
            hipMemsetAsync(dst, 0, embBytes, stream);
            spmm_scatter_kernel<<<sgrid, block, 0, stream>>>(src, row, col, vals, dst, E);
            norm_accum_kernel<<<ngrid, block, 0, stream>>>(dst, out, coefs[i], N);
            src = dst;
            float* t = dst; dst = other; other = t;
        }
    }
}